// Round 22
// baseline (403.312 us; speedup 1.0000x reference)
//
#include <hip/hip_runtime.h>
#include <math.h>
#include <stddef.h>

#define NHEAD 4
#define DHEAD 40
#define HIDW 160
#define JKW 320
#define NGRAPH 32
#define BCAP 64   // edge bucket capacity per node (deg ~ Poisson(10); P(>63) ~ 1e-31)
#define BCOLS 768 // padded B cols per layer: 640 qkvs + 20 fused-qwb + pad
#define BREAL 660 // real cols

typedef __attribute__((ext_vector_type(8))) short short8;
typedef __attribute__((ext_vector_type(4))) float f32x4;
typedef __attribute__((ext_vector_type(2))) float f32x2;
typedef __fp16 h2 __attribute__((ext_vector_type(2)));
typedef int i32x4 __attribute__((ext_vector_type(4)));
typedef i32x4 i32x4_a4 __attribute__((aligned(4)));

__device__ inline unsigned short f2bf(float x){
  unsigned u = __float_as_uint(x);
  u += 0x7fff + ((u >> 16) & 1);
  return (unsigned short)(u >> 16);
}
__device__ inline float bf2f(unsigned short h){
  return __uint_as_float(((unsigned)h) << 16);
}
__device__ inline float fdot2(h2 a, h2 b, float c){
  return __builtin_amdgcn_fdot2(a, b, c, false);
}
__device__ inline h2 pk(float a, float b){
  return __builtin_amdgcn_cvt_pkrtz(a, b);
}
union HU { h2 h; int i; unsigned u; float f; };
__device__ inline h2 shfl_h2(h2 v, int xm){
  HU u; u.h = v; u.i = __shfl_xor(u.i, xm); return u.h;
}
__device__ inline h2 asH2(unsigned i){ HU u; u.u = i; return u.h; }

#if __has_builtin(__builtin_amdgcn_cvt_pk_f16_fp8)
__device__ inline h2 cvt8(int s){ return __builtin_amdgcn_cvt_pk_f16_fp8((short)s); }
#else
__device__ inline h2 cvt8(int s){
  f32x2 t = __builtin_amdgcn_cvt_pk_f32_fp8(s, false);
  return pk(t.x, t.y);
}
#endif

__device__ inline int lbound(const int* __restrict__ b, int N, int g){
  int lo = 0, hi = N;
  while (lo < hi){ int mid = (lo + hi) >> 1; if (b[mid] < g) lo = mid + 1; else hi = mid; }
  return lo;
}

// ---------------- fused pre-pass: zero buffers + lin_in + weight pack ----------------
// v4: packs FUSED qwb weights as B cols 640..659 (qwb is linear in hb) so the
//     QKV GEMM emits qwb directly and k_qprep is eliminated.
__global__ __launch_bounds__(256) void k_pre(const float* __restrict__ x, const float* __restrict__ W_in,
                                             const float* __restrict__ b_in, unsigned short* __restrict__ hb,
                                             const float* __restrict__ Wq, const float* __restrict__ Wk,
                                             const float* __restrict__ Wv, const float* __restrict__ Ws,
                                             const float* __restrict__ bq, const float* __restrict__ bk,
                                             const float* __restrict__ bv, const float* __restrict__ bs,
                                             const float* __restrict__ Wg1,
                                             const float* __restrict__ We, const float* __restrict__ be,
                                             unsigned short* __restrict__ Bth, float* __restrict__ bp,
                                             unsigned short* __restrict__ Btgh,
                                             int* __restrict__ cnt, float* __restrict__ gate,
                                             float* __restrict__ pooled, int N){
  const float qscale = 0.15811388300841898f; // 1/sqrt(40)
  int NL = (N*20 + 255)/256;
  int bid = blockIdx.x, tid = threadIdx.x;
  if (bid < NL){
    int idx = bid*256 + tid;
    if (idx >= N*20) return;
    int n = idx / 20, j8 = (idx % 20)*8;
    const float* xr = x + n*5;
    float x0 = xr[0], x1 = xr[1], x2 = xr[2], x3 = xr[3], x4 = xr[4];
    float v[8];
    #pragma unroll
    for (int u = 0; u < 8; ++u) v[u] = b_in[j8+u];
    #pragma unroll
    for (int c = 0; c < 5; ++c){
      float xc = (c==0)?x0:(c==1)?x1:(c==2)?x2:(c==3)?x3:x4;
      const float4 wa = *(const float4*)(W_in + c*HIDW + j8);
      const float4 wb = *(const float4*)(W_in + c*HIDW + j8 + 4);
      v[0] += xc*wa.x; v[1] += xc*wa.y; v[2] += xc*wa.z; v[3] += xc*wa.w;
      v[4] += xc*wb.x; v[5] += xc*wb.y; v[6] += xc*wb.z; v[7] += xc*wb.w;
    }
    short8 o;
    #pragma unroll
    for (int u = 0; u < 8; ++u) o[u] = (short)f2bf(v[u]);
    *(short8*)(hb + (size_t)n*JKW + j8) = o;
  } else if (bid < NL + 1166){
    int idx = (bid - NL)*256 + tid;
    if (idx < 2*BCOLS*160){                      // QKV+fused B pack
      int l = idx / (BCOLS*160), r = idx % (BCOLS*160);
      int i = r / BCOLS, j = r % BCOLS;          // i = input dim, j = out col
      unsigned short outv;
      if (j < 640){
        int sel = j / HIDW, jj = j % HIDW;
        const float* W = (sel==0) ? Wq : (sel==1) ? Wk : (sel==2) ? Wv : Ws;
        outv = f2bf(W[(size_t)l*25600 + i*HIDW + jj]);
      } else if (j < BREAL){
        int c = j - 640, h = c / 5, rr = c % 5;
        const float* wqr = Wq + (size_t)l*25600 + i*HIDW + 40*h;
        const float* xr  = (rr < 4) ? (We + l*640 + rr*160 + 40*h) : (be + l*160 + 40*h);
        float s = 0.f;
        #pragma unroll
        for (int d = 0; d < 40; ++d) s += wqr[d]*xr[d];
        outv = f2bf(s * qscale);
      } else outv = 0;
      Bth[(size_t)l*(BCOLS*160) + (size_t)j*160 + i] = outv;
    } else if (idx < 2*BCOLS*160 + 51200){
      int r = idx - 2*BCOLS*160;
      int j = r / 320, i = r % 320;
      Btgh[(size_t)j*320 + i] = f2bf(Wg1[(size_t)i*160 + j]);
    } else if (idx < 2*BCOLS*160 + 51200 + 2*BCOLS){
      int r = idx - (2*BCOLS*160 + 51200);
      int l = r / BCOLS, j = r % BCOLS;
      float bvv;
      if (j < 640){
        int sel = j / HIDW, jj = j % HIDW;
        const float* b2 = (sel==0) ? bq : (sel==1) ? bk : (sel==2) ? bv : bs;
        bvv = b2[l*160 + jj];
      } else if (j < BREAL){
        int c = j - 640, h = c / 5, rr = c % 5;
        const float* bqr = bq + l*160 + 40*h;
        const float* xr  = (rr < 4) ? (We + l*640 + rr*160 + 40*h) : (be + l*160 + 40*h);
        float s = 0.f;
        #pragma unroll
        for (int d = 0; d < 40; ++d) s += bqr[d]*xr[d];
        bvv = s * qscale;
      } else bvv = 0.f;
      bp[l*BCOLS + j] = bvv;
    }
  } else {
    int idx = (bid - NL - 1166)*256 + tid;
    if (idx < N){ cnt[idx] = 0; gate[idx] = 0.f; }
    if (idx < NGRAPH*JKW) pooled[idx] = 0.f;
  }
}

// ---------------- bucketed edge fill ----------------
__global__ __launch_bounds__(256) void k_fill(const int* __restrict__ dst, const int* __restrict__ src,
                                              const float* __restrict__ edge_attr, int E,
                                              int* __restrict__ cnt, uint4* __restrict__ edges){
  int e = blockIdx.x*256 + threadIdx.x;
  if (e < E){
    int d = dst[e];
    int p = atomicAdd(&cnt[d], 1);
    if (p < BCAP){
      float4 ea = *(const float4*)(edge_attr + (size_t)e*4);
      HU a, b; a.h = pk(ea.x, ea.y); b.h = pk(ea.z, ea.w);
      edges[(size_t)d*BCAP + p] = make_uint4((unsigned)src[e], a.u, b.u, 0u);
    }
  }
}

// ---------------- bf16 MFMA GEMM v15: v13 + SPLIT-STAGE overlap in MODE 1 ----------------
// R20 counters (53us, MfmaUtil 8.8%, occ 24%): each block's critical path begins
// with a fully-exposed 41KB stage. v15 stages HALF the panel, barriers, then
// issues the other half's stores and computes s=0..3 while they are in flight
// (A fragments held in regs across both halves; +40 VGPR, still LDS-capped at
// 3 blocks/CU). Identical arithmetic/indices -- pure reorder.
#define BSTR 40
#define BSTR1 164
template<int NSUB, int MODE>
__global__ __launch_bounds__(256) void k_mgemm(const unsigned short* __restrict__ A, int lda,
                                               const unsigned short* __restrict__ Bh,
                                               const float* __restrict__ bias,
                                               _Float16* __restrict__ qh,
                                               unsigned char* __restrict__ kv8,
                                               _Float16* __restrict__ rskip,
                                               float* __restrict__ qwb,
                                               const float* __restrict__ Wg2,
                                               float* __restrict__ gate,
                                               int M, int K){
  __shared__ short sBh[(MODE==1) ? (16*NSUB*BSTR1) : (2*16*NSUB*BSTR)];
  int tid = threadIdx.x;
  int wv = tid >> 6, lane = tid & 63;
  int quad = lane >> 4, l16 = lane & 15;

  int P = gridDim.x, MBy = gridDim.y;
  int bid = blockIdx.y * P + blockIdx.x;
  int fullRows = (MBy >> 3) << 3;
  int rowB, panel;
  if (bid < fullRows * P){
    int group = bid / (8*P), rem = bid % (8*P);
    rowB  = group*8 + (rem & 7);
    panel = rem >> 3;
  } else {
    int rem = bid - fullRows*P;
    int R = MBy - fullRows;
    panel = rem / R;
    rowB  = fullRows + rem % R;
  }
  int m0 = rowB*128 + wv*32;
  int col0 = panel * (16*NSUB);

  int ar0 = m0 + l16;      if (ar0 >= M) ar0 = M - 1;
  int ar1 = m0 + 16 + l16; if (ar1 >= M) ar1 = M - 1;
  const unsigned short* Ap0 = A + (size_t)ar0*lda + quad*8;
  const unsigned short* Ap1 = A + (size_t)ar1*lda + quad*8;

  f32x4 acc[2][NSUB];
  #pragma unroll
  for (int g = 0; g < 2; ++g)
    #pragma unroll
    for (int s = 0; s < NSUB; ++s) acc[g][s] = (f32x4){0.f,0.f,0.f,0.f};

  if constexpr (MODE == 1){
    const int HALF = 16*NSUB*20/2;               // elements in half the panel
    const int HC = NSUB*8;                       // half col count
    // phase 1: stage first half
    for (int u = tid; u < HALF; u += 256){
      int col = u / 20, q = u % 20;
      *(short8*)(&sBh[col*BSTR1 + q*8]) =
        *(const short8*)(Bh + (size_t)(col0 + col)*K + q*8);
    }
    __syncthreads();
    // phase 2: issue second-half stores, then compute first half (stores in flight)
    for (int u = tid; u < HALF; u += 256){
      int col = HC + u / 20, q = u % 20;
      *(short8*)(&sBh[col*BSTR1 + q*8]) =
        *(const short8*)(Bh + (size_t)(col0 + col)*K + q*8);
    }
    short8 ahh0[5], ahh1[5];
    #pragma unroll
    for (int kk = 0; kk < 5; ++kk){
      int k0 = kk << 5;
      ahh0[kk] = *(const short8*)(Ap0 + k0);
      ahh1[kk] = *(const short8*)(Ap1 + k0);
      #pragma unroll
      for (int s = 0; s < NSUB/2; ++s){
        short8 bh = *(const short8*)(&sBh[(s*16 + l16)*BSTR1 + k0 + quad*8]);
        acc[0][s] = __builtin_amdgcn_mfma_f32_16x16x32_bf16(bh, ahh0[kk], acc[0][s], 0, 0, 0);
        acc[1][s] = __builtin_amdgcn_mfma_f32_16x16x32_bf16(bh, ahh1[kk], acc[1][s], 0, 0, 0);
      }
    }
    __syncthreads();
    // phase 3: compute second half (A fragments already live)
    #pragma unroll
    for (int kk = 0; kk < 5; ++kk){
      int k0 = kk << 5;
      #pragma unroll
      for (int s = NSUB/2; s < NSUB; ++s){
        short8 bh = *(const short8*)(&sBh[(s*16 + l16)*BSTR1 + k0 + quad*8]);
        acc[0][s] = __builtin_amdgcn_mfma_f32_16x16x32_bf16(bh, ahh0[kk], acc[0][s], 0, 0, 0);
        acc[1][s] = __builtin_amdgcn_mfma_f32_16x16x32_bf16(bh, ahh1[kk], acc[1][s], 0, 0, 0);
      }
    }
  } else {
    const int CH = K >> 5;
    for (int u = tid; u < 16*NSUB*4; u += 256){
      int col = u >> 2, q4 = u & 3;
      *(short8*)(&sBh[col*BSTR + q4*8]) =
        *(const short8*)(Bh + (size_t)(col0 + col)*K + q4*8);
    }
    __syncthreads();
    int buf = 0;
    for (int kk = 0; kk < CH; ++kk){
      int k0 = kk << 5;
      if (kk + 1 < CH){
        int kn = k0 + 32;
        for (int u = tid; u < 16*NSUB*4; u += 256){
          int col = u >> 2, q4 = u & 3;
          *(short8*)(&sBh[(buf^1)*16*NSUB*BSTR + col*BSTR + q4*8]) =
            *(const short8*)(Bh + (size_t)(col0 + col)*K + kn + q4*8);
        }
      }
      short8 ah0 = *(const short8*)(Ap0 + k0);
      short8 ah1 = *(const short8*)(Ap1 + k0);
      #pragma unroll
      for (int s = 0; s < NSUB; ++s){
        short8 bh = *(const short8*)(&sBh[buf*16*NSUB*BSTR + (s*16 + l16)*BSTR + quad*8]);
        acc[0][s] = __builtin_amdgcn_mfma_f32_16x16x32_bf16(bh, ah0, acc[0][s], 0, 0, 0);
        acc[1][s] = __builtin_amdgcn_mfma_f32_16x16x32_bf16(bh, ah1, acc[1][s], 0, 0, 0);
      }
      __syncthreads();
      buf ^= 1;
    }
  }

  const float qscale = 0.15811388300841898f; // 1/sqrt(40)
  if (MODE == 1){
    #pragma unroll
    for (int g = 0; g < 2; ++g){
      int row = m0 + g*16 + l16;
      if (row >= M) continue;
      #pragma unroll
      for (int s = 0; s < NSUB; ++s){
        int col4 = col0 + s*16 + quad*4;
        int sel = col4 / 160, cc4 = col4 % 160;
        const float4 bv = *(const float4*)(bias + col4);
        float v0 = acc[g][s][0] + bv.x;
        float v1 = acc[g][s][1] + bv.y;
        float v2 = acc[g][s][2] + bv.z;
        float v3 = acc[g][s][3] + bv.w;
        if (sel == 0){
          HU a, b; a.h = pk(v0*qscale, v1*qscale); b.h = pk(v2*qscale, v3*qscale);
          *(uint2*)(qh + (size_t)row*160 + cc4) = make_uint2(a.u, b.u);
        } else if (sel == 3){
          HU a, b; a.h = pk(v0, v1); b.h = pk(v2, v3);
          *(uint2*)(rskip + (size_t)row*160 + cc4) = make_uint2(a.u, b.u);
        } else if (sel >= 4){
          if (col4 < BREAL){
            float4 o4; o4.x = v0; o4.y = v1; o4.z = v2; o4.w = v3;
            *(float4*)(qwb + (size_t)row*20 + (col4 - 640)) = o4;
          }
        } else {
          int slot = (cc4/40)*4 + (cc4%40)/10, j = cc4%10;
          int off = (sel==2) ? 10 : 0;
          unsigned short e01 = (unsigned short)(__builtin_amdgcn_cvt_pk_fp8_f32(v0, v1, 0, false) & 0xffff);
          unsigned short e23 = (unsigned short)(__builtin_amdgcn_cvt_pk_fp8_f32(v2, v3, 0, false) & 0xffff);
          unsigned char* base = kv8 + (size_t)row*320;
          if (j <= 6){
            *(unsigned short*)(base + slot*20 + off + j)     = e01;
            *(unsigned short*)(base + slot*20 + off + j + 2) = e23;
          } else {
            *(unsigned short*)(base + slot*20 + off + 8)     = e01;
            *(unsigned short*)(base + (slot+1)*20 + off + 0) = e23;
          }
        }
      }
    }
  } else {
    float vg0 = 0.f, vg1 = 0.f;
    #pragma unroll
    for (int s = 0; s < NSUB; ++s){
      int col4 = col0 + s*16 + quad*4;
      const float4 bv = *(const float4*)(bias + col4);
      const float4 wg = *(const float4*)(Wg2 + col4);
      vg0 += fmaxf(acc[0][s][0]+bv.x,0.f)*wg.x + fmaxf(acc[0][s][1]+bv.y,0.f)*wg.y
           + fmaxf(acc[0][s][2]+bv.z,0.f)*wg.z + fmaxf(acc[0][s][3]+bv.w,0.f)*wg.w;
      vg1 += fmaxf(acc[1][s][0]+bv.x,0.f)*wg.x + fmaxf(acc[1][s][1]+bv.y,0.f)*wg.y
           + fmaxf(acc[1][s][2]+bv.z,0.f)*wg.z + fmaxf(acc[1][s][3]+bv.w,0.f)*wg.w;
    }
    vg0 += __shfl_xor(vg0, 16); vg0 += __shfl_xor(vg0, 32);
    vg1 += __shfl_xor(vg1, 16); vg1 += __shfl_xor(vg1, 32);
    if (quad == 0){
      int row0 = m0 + l16, row1 = m0 + 16 + l16;
      if (row0 < M) gate[row0] = vg0;
      if (row1 < M) gate[row1] = vg1;
    }
  }
}

// ---------------- fused edge attention + beta gate (fp8 kv, no-max softmax) ----------------
__global__ __launch_bounds__(256) void k_attn(const _Float16* __restrict__ qh,
                                              const unsigned char* __restrict__ kv8,
                                              const _Float16* __restrict__ rskip,
                                              const float* __restrict__ qwb,
                                              const uint4* __restrict__ edges,
                                              const int* __restrict__ cnt,
                                              const float* __restrict__ We, const float* __restrict__ be,
                                              const float* __restrict__ Wb,
                                              unsigned short* __restrict__ hb,
                                              int loff, int N){
  int tid = threadIdx.x;
  int grp = tid >> 4;
  int n = blockIdx.x*16 + grp;
  bool valid = (n < N);
  int nn = valid ? n : (N-1);
  int w = tid & 15;
  int hh = w & 3, t = w >> 2;
  int cbase = DHEAD*hh + 10*t;
  int slot = hh*4 + t;

  h2 qh2[5];
  {
    const unsigned* qp = (const unsigned*)(qh + (size_t)nn*160 + cbase);
    #pragma unroll
    for (int i = 0; i < 5; ++i) qh2[i] = asH2(qp[i]);
  }
  const float* qwp = qwb + (size_t)nn*20 + hh*5;
  float qw0 = qwp[0], qw1 = qwp[1], qw2 = qwp[2], qw3 = qwp[3], qb = qwp[4];
  h2 qw01 = pk(qw0, qw1), qw23 = pk(qw2, qw3);

  float ssum = 0.f;
  h2 zh = pk(0.f, 0.f);
  h2 acch[5], sah[2];
  #pragma unroll
  for (int i = 0; i < 5; ++i) acch[i] = zh;
  sah[0] = zh; sah[1] = zh;

  int deg = 0;
  if (valid){ deg = cnt[nn]; if (deg > BCAP) deg = BCAP; }
  int st = nn*BCAP;

  uint4 r0 = make_uint4(0,0,0,0), r1 = make_uint4(0,0,0,0);
  uint4 r2 = make_uint4(0,0,0,0), r3 = make_uint4(0,0,0,0);
  i32x4 k0v = {0,0,0,0}, k1v = {0,0,0,0}; int k0e = 0, k1e = 0;
  if (deg > 0) r0 = edges[st];
  if (deg > 1) r1 = edges[st+1];
  if (deg > 2) r2 = edges[st+2];
  if (deg > 3) r3 = edges[st+3];
  if (deg > 0){
    const unsigned char* kp = kv8 + (size_t)r0.x*320 + slot*20;
    k0v = *(const i32x4_a4*)kp; k0e = *(const int*)(kp+16);
  }
  if (deg > 1){
    const unsigned char* kp = kv8 + (size_t)r1.x*320 + slot*20;
    k1v = *(const i32x4_a4*)kp; k1e = *(const int*)(kp+16);
  }

  for (int e = 0; e < deg; e += 2){
    uint4 n0 = make_uint4(0,0,0,0), n1 = make_uint4(0,0,0,0);
    if (e + 4 < deg) n0 = edges[st + e + 4];
    if (e + 5 < deg) n1 = edges[st + e + 5];
    i32x4 k2v = {0,0,0,0}, k3v = {0,0,0,0}; int k2e = 0, k3e = 0;
    if (e + 2 < deg){
      const unsigned char* kp = kv8 + (size_t)r2.x*320 + slot*20;
      k2v = *(const i32x4_a4*)kp; k2e = *(const int*)(kp+16);
    }
    if (e + 3 < deg){
      const unsigned char* kp = kv8 + (size_t)r3.x*320 + slot*20;
      k3v = *(const i32x4_a4*)kp; k3e = *(const int*)(kp+16);
    }
    bool v1 = (e + 1 < deg);
    h2 ea00 = asH2(r0.y), ea01 = asH2(r0.z);
    h2 ea10 = asH2(r1.y), ea11 = asH2(r1.z);
    float p0 = 0.f, p1 = 0.f;
    p0 = fdot2(qh2[0], cvt8(k0v.x), p0);       p1 = fdot2(qh2[0], cvt8(k1v.x), p1);
    p0 = fdot2(qh2[1], cvt8(k0v.x >> 16), p0); p1 = fdot2(qh2[1], cvt8(k1v.x >> 16), p1);
    p0 = fdot2(qh2[2], cvt8(k0v.y), p0);       p1 = fdot2(qh2[2], cvt8(k1v.y), p1);
    p0 = fdot2(qh2[3], cvt8(k0v.y >> 16), p0); p1 = fdot2(qh2[3], cvt8(k1v.y >> 16), p1);
    p0 = fdot2(qh2[4], cvt8(k0v.z), p0);       p1 = fdot2(qh2[4], cvt8(k1v.z), p1);
    p0 += __shfl_xor(p0, 4);                   p1 += __shfl_xor(p1, 4);
    p0 += __shfl_xor(p0, 8);                   p1 += __shfl_xor(p1, 8);
    p0 += qb;                                  p1 += qb;
    p0 = fdot2(ea00, qw01, p0);                p1 = fdot2(ea10, qw01, p1);
    p0 = fdot2(ea01, qw23, p0);                p1 = fdot2(ea11, qw23, p1);

    float ex0 = __expf(p0);
    float ex1 = v1 ? __expf(p1) : 0.f;
    ssum += ex0;
    ssum += ex1;
    h2 eh0 = pk(ex0, ex0), eh1 = pk(ex1, ex1);
    acch[0] += cvt8(k0v.z >> 16)*eh0;  acch[0] += cvt8(k1v.z >> 16)*eh1;
    acch[1] += cvt8(k0v.w)*eh0;        acch[1] += cvt8(k1v.w)*eh1;
    acch[2] += cvt8(k0v.w >> 16)*eh0;  acch[2] += cvt8(k1v.w >> 16)*eh1;
    acch[3] += cvt8(k0e)*eh0;          acch[3] += cvt8(k1e)*eh1;
    acch[4] += cvt8(k0e >> 16)*eh0;    acch[4] += cvt8(k1e >> 16)*eh1;
    sah[0] += ea00*eh0;                sah[0] += ea10*eh1;
    sah[1] += ea01*eh0;                sah[1] += ea11*eh1;

    r0 = r2; r1 = r3; r2 = n0; r3 = n1;
    k0v = k2v; k0e = k2e; k1v = k3v; k1e = k3e;
  }

  {
    float inv = (ssum > 0.f) ? 1.f/ssum : 0.f;
    float sw0 = (float)sah[0].x*inv, sw1 = (float)sah[0].y*inv;
    float sw2 = (float)sah[1].x*inv, sw3 = (float)sah[1].y*inv;
    float bterm = (ssum > 0.f) ? 1.f : 0.f;

    const unsigned* rpu = (const unsigned*)(rskip + (size_t)nn*160 + cbase);
    float o[10];
    float part = 0.f;
    #pragma unroll
    for (int i = 0; i < 5; ++i){
      int c = cbase + 2*i;
      float o0 = (float)acch[i].x*inv + sw0*We[c]   + sw1*We[160+c] + sw2*We[320+c] + sw3*We[480+c] + bterm*be[c];
      float o1 = (float)acch[i].y*inv + sw0*We[c+1] + sw1*We[161+c] + sw2*We[321+c] + sw3*We[481+c] + bterm*be[c+1];
      HU u; u.u = rpu[i];
      float r0f = (float)u.h.x, r1f = (float)u.h.y;
      part += o0*Wb[c]   + r0f*Wb[160+c] + (o0-r0f)*Wb[320+c];
      part += o1*Wb[c+1] + r1f*Wb[161+c] + (o1-r1f)*Wb[321+c];
      o[2*i] = o0; o[2*i+1] = o1;
    }
    part += __shfl_xor(part, 1); part += __shfl_xor(part, 2);
    part += __shfl_xor(part, 4); part += __shfl_xor(part, 8);
    float beta = 1.f/(1.f + __expf(-part));
    if (valid){
      unsigned* hp32 = (unsigned*)(hb + (size_t)nn*JKW + loff);
      #pragma unroll
      for (int i = 0; i < 5; ++i){
        HU u; u.u = rpu[i];
        float r0f = (float)u.h.x, r1f = (float)u.h.y;
        unsigned lo = f2bf(beta*r0f + (1.f-beta)*o[2*i]);
        unsigned hi = f2bf(beta*r1f + (1.f-beta)*o[2*i+1]);
        hp32[cbase/2 + i] = lo | (hi << 16);
      }
    }
  }
}

// ---------------- per-graph gate stats + in-place att normalization ----------------
__global__ __launch_bounds__(256) void k_gatt(float* __restrict__ gate, const int* __restrict__ batch, int N){
  __shared__ float sm[256];
  int g = blockIdx.x, j = threadIdx.x;
  int lo = lbound(batch, N, g), hi = lbound(batch, N, g+1);
  if (hi <= lo) return;
  float m = -INFINITY;
  for (int i = lo + j; i < hi; i += 256) m = fmaxf(m, gate[i]);
  sm[j] = m; __syncthreads();
  #pragma unroll
  for (int off = 128; off; off >>= 1){
    if (j < off) sm[j] = fmaxf(sm[j], sm[j+off]);
    __syncthreads();
  }
  float gm = sm[0]; __syncthreads();
  float s = 0.f;
  for (int i = lo + j; i < hi; i += 256) s += __expf(gate[i] - gm);
  sm[j] = s; __syncthreads();
  #pragma unroll
  for (int off = 128; off; off >>= 1){
    if (j < off) sm[j] += sm[j+off];
    __syncthreads();
  }
  float dg = sm[0];
  float invd = (dg > 0.f) ? 1.f/dg : 0.f;
  for (int i = lo + j; i < hi; i += 256) gate[i] = __expf(gate[i] - gm) * invd;
}

// ---------------- attention pooling: pure weighted accumulation ----------------
__global__ __launch_bounds__(320) void k_pool(const unsigned short* __restrict__ hb, const float* __restrict__ gate,
                                              const int* __restrict__ batch, int N,
                                              float* __restrict__ pooled){
  int g = blockIdx.x, part = blockIdx.y, j = threadIdx.x;
  int lo = lbound(batch, N, g), hi = lbound(batch, N, g+1);
  int len = hi - lo;
  if (len <= 0) return;
  int chunk = (len + (int)gridDim.y - 1) / (int)gridDim.y;
  int a = lo + part*chunk;
  int bnd = a + chunk; if (bnd > hi) bnd = hi;
  if (a >= bnd) return;
  float acc = 0.f;
  #pragma unroll 2
  for (int n = a; n < bnd; ++n){
    acc += gate[n] * bf2f(hb[(size_t)n*JKW + j]);
  }
  atomicAdd(&pooled[g*JKW + j], acc);
}

__global__ __launch_bounds__(320) void k_head(const float* __restrict__ pooled, const float* __restrict__ Wh1,
                                              const float* __restrict__ bh1, const float* __restrict__ Wh2,
                                              const float* __restrict__ bh2, float* __restrict__ out){
  __shared__ float p[320];
  __shared__ float t[320];
  int g = blockIdx.x, tid = threadIdx.x;
  p[tid] = pooled[g*JKW + tid]; __syncthreads();
  float a = bh1[tid];
  for (int i = 0; i < 320; ++i) a += p[i]*Wh1[i*JKW + tid];
  t[tid] = fmaxf(a, 0.f); __syncthreads();
  if (tid < 6){
    float o = bh2[tid];
    for (int j = 0; j < 320; ++j) o += t[j]*Wh2[j*6 + tid];
    out[g*6 + tid] = o;
  }
}

extern "C" void kernel_launch(void* const* d_in, const int* in_sizes, int n_in,
                              void* d_out, int out_size, void* d_ws, size_t ws_size,
                              hipStream_t stream){
  (void)n_in; (void)out_size; (void)ws_size;
  const float* x        = (const float*)d_in[0];
  const int*   eidx     = (const int*)d_in[1];
  const float* edge_attr= (const float*)d_in[2];
  const int*   batch    = (const int*)d_in[3];
  const float* W_in     = (const float*)d_in[4];
  const float* b_in     = (const float*)d_in[5];
  const float* Wq       = (const float*)d_in[6];
  const float* bq       = (const float*)d_in[7];
  const float* Wk       = (const float*)d_in[8];
  const float* bk       = (const float*)d_in[9];
  const float* Wv       = (const float*)d_in[10];
  const float* bv       = (const float*)d_in[11];
  const float* We       = (const float*)d_in[12];
  const float* be       = (const float*)d_in[13];
  const float* Wsk      = (const float*)d_in[14];
  const float* bsk      = (const float*)d_in[15];
  const float* Wb       = (const float*)d_in[16];
  const float* Wg1      = (const float*)d_in[17];
  const float* bg1      = (const float*)d_in[18];
  const float* Wg2      = (const float*)d_in[19];
  const float* Wh1      = (const float*)d_in[21];
  const float* bh1      = (const float*)d_in[22];
  const float* Wh2      = (const float*)d_in[23];
  const float* bh2      = (const float*)d_in[24];

  const int N = in_sizes[0] / 5;
  const int E = in_sizes[1] / 2;
  float* out = (float*)d_out;

  char* w = (char*)d_ws;
  auto alloc = [&](size_t bytes)->char*{ char* p = w; w += (bytes + 255) & ~(size_t)255; return p; };
  unsigned short* hb = (unsigned short*)alloc((size_t)N*JKW*2);
  _Float16* qh  = (_Float16*)alloc((size_t)N*160*2);
  unsigned char* kv8 = (unsigned char*)alloc((size_t)N*320);
  _Float16* rskip = (_Float16*)alloc((size_t)N*160*2);
  float* qwb    = (float*)alloc((size_t)N*20*4);
  unsigned short* Bth  = (unsigned short*)alloc((size_t)2*BCOLS*160*2);
  unsigned short* Btgh = (unsigned short*)alloc((size_t)160*320*2);
  float* bpack  = (float*)alloc((size_t)2*BCOLS*4);
  int*   cnt    = (int*)alloc((size_t)N*4);
  uint4* edges  = (uint4*)alloc((size_t)N*BCAP*16);
  float* gate   = (float*)alloc((size_t)N*4);
  float* pooled = (float*)alloc(NGRAPH*JKW*4);

  const int* srcI = eidx;
  const int* dstI = eidx + E;

  const int NL = (N*20 + 255)/256;
  const int NZ = (N + 255)/256;
  k_pre<<<NL + 1166 + NZ, 256, 0, stream>>>(x, W_in, b_in, hb,
                                            Wq, Wk, Wv, Wsk, bq, bk, bv, bsk, Wg1, We, be,
                                            Bth, bpack, Btgh, cnt, gate, pooled, N);

  const int eb = (E + 255)/256;
  k_fill<<<eb, 256, 0, stream>>>(dstI, srcI, edge_attr, E, cnt, edges);

  const int MB128 = (N + 127)/128;
  for (int l = 0; l < 2; ++l){
    dim3 g1(6, MB128);   // 6 x 128-col panels covering 660 real cols (qkvs + fused qwb)
    k_mgemm<8,1><<<g1, 256, 0, stream>>>(hb, JKW, Bth + (size_t)l*(BCOLS*160), bpack + l*BCOLS,
                                         qh, kv8, rskip, qwb, nullptr, nullptr, N, HIDW);
    k_attn<<<(N + 15)/16, 256, 0, stream>>>(qh, kv8, rskip, qwb, edges, cnt,
                                            We + l*640, be + l*160, Wb + l*480, hb, l*HIDW, N);
  }

  k_mgemm<10,2><<<dim3(1, MB128), 256, 0, stream>>>(hb, JKW, Btgh, bg1, nullptr, nullptr, nullptr, nullptr,
                                                    Wg2, gate, N, JKW);

  k_gatt<<<NGRAPH, 256, 0, stream>>>(gate, batch, N);
  dim3 g3(NGRAPH, 32);
  k_pool<<<g3, 320, 0, stream>>>(hb, gate, batch, N, pooled);
  k_head<<<NGRAPH, 320, 0, stream>>>(pooled, Wh1, bh1, Wh2, bh2, out);
}

// Round 24
// 399.627 us; speedup vs baseline: 1.0092x; 1.0092x over previous
//
#include <hip/hip_runtime.h>
#include <math.h>
#include <stddef.h>

#define NHEAD 4
#define DHEAD 40
#define HIDW 160
#define JKW 320
#define NGRAPH 32
#define BCAP 64   // edge bucket capacity per node (deg ~ Poisson(10); P(>63) ~ 1e-31)
#define BCOLS 768 // padded B cols per layer: 640 qkvs + 20 fused-qwb + pad
#define BREAL 660 // real cols

typedef __attribute__((ext_vector_type(8))) short short8;
typedef __attribute__((ext_vector_type(4))) float f32x4;
typedef __attribute__((ext_vector_type(2))) float f32x2;
typedef __fp16 h2 __attribute__((ext_vector_type(2)));
typedef int i32x4 __attribute__((ext_vector_type(4)));
typedef i32x4 i32x4_a4 __attribute__((aligned(4)));

__device__ inline unsigned short f2bf(float x){
  unsigned u = __float_as_uint(x);
  u += 0x7fff + ((u >> 16) & 1);
  return (unsigned short)(u >> 16);
}
__device__ inline float bf2f(unsigned short h){
  return __uint_as_float(((unsigned)h) << 16);
}
__device__ inline float fdot2(h2 a, h2 b, float c){
  return __builtin_amdgcn_fdot2(a, b, c, false);
}
__device__ inline h2 pk(float a, float b){
  return __builtin_amdgcn_cvt_pkrtz(a, b);
}
union HU { h2 h; int i; unsigned u; float f; };
__device__ inline h2 shfl_h2(h2 v, int xm){
  HU u; u.h = v; u.i = __shfl_xor(u.i, xm); return u.h;
}
__device__ inline h2 asH2(unsigned i){ HU u; u.u = i; return u.h; }

#if __has_builtin(__builtin_amdgcn_cvt_pk_f16_fp8)
__device__ inline h2 cvt8(int s){ return __builtin_amdgcn_cvt_pk_f16_fp8((short)s); }
#else
__device__ inline h2 cvt8(int s){
  f32x2 t = __builtin_amdgcn_cvt_pk_f32_fp8(s, false);
  return pk(t.x, t.y);
}
#endif

__device__ inline int lbound(const int* __restrict__ b, int N, int g){
  int lo = 0, hi = N;
  while (lo < hi){ int mid = (lo + hi) >> 1; if (b[mid] < g) lo = mid + 1; else hi = mid; }
  return lo;
}

// ---------------- fused pre-pass: zero buffers + lin_in + weight pack ----------------
// v4: packs FUSED qwb weights as B cols 640..659 (qwb is linear in hb) so the
//     QKV GEMM emits qwb directly and k_qprep is eliminated.
__global__ __launch_bounds__(256) void k_pre(const float* __restrict__ x, const float* __restrict__ W_in,
                                             const float* __restrict__ b_in, unsigned short* __restrict__ hb,
                                             const float* __restrict__ Wq, const float* __restrict__ Wk,
                                             const float* __restrict__ Wv, const float* __restrict__ Ws,
                                             const float* __restrict__ bq, const float* __restrict__ bk,
                                             const float* __restrict__ bv, const float* __restrict__ bs,
                                             const float* __restrict__ Wg1,
                                             const float* __restrict__ We, const float* __restrict__ be,
                                             unsigned short* __restrict__ Bth, float* __restrict__ bp,
                                             unsigned short* __restrict__ Btgh,
                                             int* __restrict__ cnt, float* __restrict__ gate,
                                             float* __restrict__ pooled, int N){
  const float qscale = 0.15811388300841898f; // 1/sqrt(40)
  int NL = (N*20 + 255)/256;
  int bid = blockIdx.x, tid = threadIdx.x;
  if (bid < NL){
    int idx = bid*256 + tid;
    if (idx >= N*20) return;
    int n = idx / 20, j8 = (idx % 20)*8;
    const float* xr = x + n*5;
    float x0 = xr[0], x1 = xr[1], x2 = xr[2], x3 = xr[3], x4 = xr[4];
    float v[8];
    #pragma unroll
    for (int u = 0; u < 8; ++u) v[u] = b_in[j8+u];
    #pragma unroll
    for (int c = 0; c < 5; ++c){
      float xc = (c==0)?x0:(c==1)?x1:(c==2)?x2:(c==3)?x3:x4;
      const float4 wa = *(const float4*)(W_in + c*HIDW + j8);
      const float4 wb = *(const float4*)(W_in + c*HIDW + j8 + 4);
      v[0] += xc*wa.x; v[1] += xc*wa.y; v[2] += xc*wa.z; v[3] += xc*wa.w;
      v[4] += xc*wb.x; v[5] += xc*wb.y; v[6] += xc*wb.z; v[7] += xc*wb.w;
    }
    short8 o;
    #pragma unroll
    for (int u = 0; u < 8; ++u) o[u] = (short)f2bf(v[u]);
    *(short8*)(hb + (size_t)n*JKW + j8) = o;
  } else if (bid < NL + 1166){
    int idx = (bid - NL)*256 + tid;
    if (idx < 2*BCOLS*160){                      // QKV+fused B pack
      int l = idx / (BCOLS*160), r = idx % (BCOLS*160);
      int i = r / BCOLS, j = r % BCOLS;          // i = input dim, j = out col
      unsigned short outv;
      if (j < 640){
        int sel = j / HIDW, jj = j % HIDW;
        const float* W = (sel==0) ? Wq : (sel==1) ? Wk : (sel==2) ? Wv : Ws;
        outv = f2bf(W[(size_t)l*25600 + i*HIDW + jj]);
      } else if (j < BREAL){
        int c = j - 640, h = c / 5, rr = c % 5;
        const float* wqr = Wq + (size_t)l*25600 + i*HIDW + 40*h;
        const float* xr  = (rr < 4) ? (We + l*640 + rr*160 + 40*h) : (be + l*160 + 40*h);
        float s = 0.f;
        #pragma unroll
        for (int d = 0; d < 40; ++d) s += wqr[d]*xr[d];
        outv = f2bf(s * qscale);
      } else outv = 0;
      Bth[(size_t)l*(BCOLS*160) + (size_t)j*160 + i] = outv;
    } else if (idx < 2*BCOLS*160 + 51200){
      int r = idx - 2*BCOLS*160;
      int j = r / 320, i = r % 320;
      Btgh[(size_t)j*320 + i] = f2bf(Wg1[(size_t)i*160 + j]);
    } else if (idx < 2*BCOLS*160 + 51200 + 2*BCOLS){
      int r = idx - (2*BCOLS*160 + 51200);
      int l = r / BCOLS, j = r % BCOLS;
      float bvv;
      if (j < 640){
        int sel = j / HIDW, jj = j % HIDW;
        const float* b2 = (sel==0) ? bq : (sel==1) ? bk : (sel==2) ? bv : bs;
        bvv = b2[l*160 + jj];
      } else if (j < BREAL){
        int c = j - 640, h = c / 5, rr = c % 5;
        const float* bqr = bq + l*160 + 40*h;
        const float* xr  = (rr < 4) ? (We + l*640 + rr*160 + 40*h) : (be + l*160 + 40*h);
        float s = 0.f;
        #pragma unroll
        for (int d = 0; d < 40; ++d) s += bqr[d]*xr[d];
        bvv = s * qscale;
      } else bvv = 0.f;
      bp[l*BCOLS + j] = bvv;
    }
  } else {
    int idx = (bid - NL - 1166)*256 + tid;
    if (idx < N){ cnt[idx] = 0; gate[idx] = 0.f; }
    if (idx < NGRAPH*JKW) pooled[idx] = 0.f;
  }
}

// ---------------- bucketed edge fill ----------------
__global__ __launch_bounds__(256) void k_fill(const int* __restrict__ dst, const int* __restrict__ src,
                                              const float* __restrict__ edge_attr, int E,
                                              int* __restrict__ cnt, uint4* __restrict__ edges){
  int e = blockIdx.x*256 + threadIdx.x;
  if (e < E){
    int d = dst[e];
    int p = atomicAdd(&cnt[d], 1);
    if (p < BCAP){
      float4 ea = *(const float4*)(edge_attr + (size_t)e*4);
      HU a, b; a.h = pk(ea.x, ea.y); b.h = pk(ea.z, ea.w);
      edges[(size_t)d*BCAP + p] = make_uint4((unsigned)src[e], a.u, b.u, 0u);
    }
  }
}

// ---------------- bf16 MFMA GEMM v13: NSUB=8 LDS stage + packed stores + fused qwb ----------------
// SESSION FINAL (measured 402.0us total @ R20).
#define BSTR 40
#define BSTR1 164
template<int NSUB, int MODE>
__global__ __launch_bounds__(256) void k_mgemm(const unsigned short* __restrict__ A, int lda,
                                               const unsigned short* __restrict__ Bh,
                                               const float* __restrict__ bias,
                                               _Float16* __restrict__ qh,
                                               unsigned char* __restrict__ kv8,
                                               _Float16* __restrict__ rskip,
                                               float* __restrict__ qwb,
                                               const float* __restrict__ Wg2,
                                               float* __restrict__ gate,
                                               int M, int K){
  __shared__ short sBh[(MODE==1) ? (16*NSUB*BSTR1) : (2*16*NSUB*BSTR)];
  int tid = threadIdx.x;
  int wv = tid >> 6, lane = tid & 63;
  int quad = lane >> 4, l16 = lane & 15;

  int P = gridDim.x, MBy = gridDim.y;
  int bid = blockIdx.y * P + blockIdx.x;
  int fullRows = (MBy >> 3) << 3;
  int rowB, panel;
  if (bid < fullRows * P){
    int group = bid / (8*P), rem = bid % (8*P);
    rowB  = group*8 + (rem & 7);
    panel = rem >> 3;
  } else {
    int rem = bid - fullRows*P;
    int R = MBy - fullRows;
    panel = rem / R;
    rowB  = fullRows + rem % R;
  }
  int m0 = rowB*128 + wv*32;
  int col0 = panel * (16*NSUB);

  int ar0 = m0 + l16;      if (ar0 >= M) ar0 = M - 1;
  int ar1 = m0 + 16 + l16; if (ar1 >= M) ar1 = M - 1;
  const unsigned short* Ap0 = A + (size_t)ar0*lda + quad*8;
  const unsigned short* Ap1 = A + (size_t)ar1*lda + quad*8;

  f32x4 acc[2][NSUB];
  #pragma unroll
  for (int g = 0; g < 2; ++g)
    #pragma unroll
    for (int s = 0; s < NSUB; ++s) acc[g][s] = (f32x4){0.f,0.f,0.f,0.f};

  if constexpr (MODE == 1){
    for (int u = tid; u < 16*NSUB*20; u += 256){
      int col = u / 20, q = u % 20;
      *(short8*)(&sBh[col*BSTR1 + q*8]) =
        *(const short8*)(Bh + (size_t)(col0 + col)*K + q*8);
    }
    __syncthreads();
    #pragma unroll
    for (int kk = 0; kk < 5; ++kk){
      int k0 = kk << 5;
      short8 ah0 = *(const short8*)(Ap0 + k0);
      short8 ah1 = *(const short8*)(Ap1 + k0);
      #pragma unroll
      for (int s = 0; s < NSUB; ++s){
        short8 bh = *(const short8*)(&sBh[(s*16 + l16)*BSTR1 + k0 + quad*8]);
        acc[0][s] = __builtin_amdgcn_mfma_f32_16x16x32_bf16(bh, ah0, acc[0][s], 0, 0, 0);
        acc[1][s] = __builtin_amdgcn_mfma_f32_16x16x32_bf16(bh, ah1, acc[1][s], 0, 0, 0);
      }
    }
  } else {
    const int CH = K >> 5;
    for (int u = tid; u < 16*NSUB*4; u += 256){
      int col = u >> 2, q4 = u & 3;
      *(short8*)(&sBh[col*BSTR + q4*8]) =
        *(const short8*)(Bh + (size_t)(col0 + col)*K + q4*8);
    }
    __syncthreads();
    int buf = 0;
    for (int kk = 0; kk < CH; ++kk){
      int k0 = kk << 5;
      if (kk + 1 < CH){
        int kn = k0 + 32;
        for (int u = tid; u < 16*NSUB*4; u += 256){
          int col = u >> 2, q4 = u & 3;
          *(short8*)(&sBh[(buf^1)*16*NSUB*BSTR + col*BSTR + q4*8]) =
            *(const short8*)(Bh + (size_t)(col0 + col)*K + kn + q4*8);
        }
      }
      short8 ah0 = *(const short8*)(Ap0 + k0);
      short8 ah1 = *(const short8*)(Ap1 + k0);
      #pragma unroll
      for (int s = 0; s < NSUB; ++s){
        short8 bh = *(const short8*)(&sBh[buf*16*NSUB*BSTR + (s*16 + l16)*BSTR + quad*8]);
        acc[0][s] = __builtin_amdgcn_mfma_f32_16x16x32_bf16(bh, ah0, acc[0][s], 0, 0, 0);
        acc[1][s] = __builtin_amdgcn_mfma_f32_16x16x32_bf16(bh, ah1, acc[1][s], 0, 0, 0);
      }
      __syncthreads();
      buf ^= 1;
    }
  }

  const float qscale = 0.15811388300841898f; // 1/sqrt(40)
  if (MODE == 1){
    #pragma unroll
    for (int g = 0; g < 2; ++g){
      int row = m0 + g*16 + l16;
      if (row >= M) continue;
      #pragma unroll
      for (int s = 0; s < NSUB; ++s){
        int col4 = col0 + s*16 + quad*4;
        int sel = col4 / 160, cc4 = col4 % 160;
        const float4 bv = *(const float4*)(bias + col4);
        float v0 = acc[g][s][0] + bv.x;
        float v1 = acc[g][s][1] + bv.y;
        float v2 = acc[g][s][2] + bv.z;
        float v3 = acc[g][s][3] + bv.w;
        if (sel == 0){
          HU a, b; a.h = pk(v0*qscale, v1*qscale); b.h = pk(v2*qscale, v3*qscale);
          *(uint2*)(qh + (size_t)row*160 + cc4) = make_uint2(a.u, b.u);
        } else if (sel == 3){
          HU a, b; a.h = pk(v0, v1); b.h = pk(v2, v3);
          *(uint2*)(rskip + (size_t)row*160 + cc4) = make_uint2(a.u, b.u);
        } else if (sel >= 4){
          if (col4 < BREAL){
            float4 o4; o4.x = v0; o4.y = v1; o4.z = v2; o4.w = v3;
            *(float4*)(qwb + (size_t)row*20 + (col4 - 640)) = o4;
          }
        } else {
          int slot = (cc4/40)*4 + (cc4%40)/10, j = cc4%10;
          int off = (sel==2) ? 10 : 0;
          unsigned short e01 = (unsigned short)(__builtin_amdgcn_cvt_pk_fp8_f32(v0, v1, 0, false) & 0xffff);
          unsigned short e23 = (unsigned short)(__builtin_amdgcn_cvt_pk_fp8_f32(v2, v3, 0, false) & 0xffff);
          unsigned char* base = kv8 + (size_t)row*320;
          if (j <= 6){
            *(unsigned short*)(base + slot*20 + off + j)     = e01;
            *(unsigned short*)(base + slot*20 + off + j + 2) = e23;
          } else {
            *(unsigned short*)(base + slot*20 + off + 8)     = e01;
            *(unsigned short*)(base + (slot+1)*20 + off + 0) = e23;
          }
        }
      }
    }
  } else {
    float vg0 = 0.f, vg1 = 0.f;
    #pragma unroll
    for (int s = 0; s < NSUB; ++s){
      int col4 = col0 + s*16 + quad*4;
      const float4 bv = *(const float4*)(bias + col4);
      const float4 wg = *(const float4*)(Wg2 + col4);
      vg0 += fmaxf(acc[0][s][0]+bv.x,0.f)*wg.x + fmaxf(acc[0][s][1]+bv.y,0.f)*wg.y
           + fmaxf(acc[0][s][2]+bv.z,0.f)*wg.z + fmaxf(acc[0][s][3]+bv.w,0.f)*wg.w;
      vg1 += fmaxf(acc[1][s][0]+bv.x,0.f)*wg.x + fmaxf(acc[1][s][1]+bv.y,0.f)*wg.y
           + fmaxf(acc[1][s][2]+bv.z,0.f)*wg.z + fmaxf(acc[1][s][3]+bv.w,0.f)*wg.w;
    }
    vg0 += __shfl_xor(vg0, 16); vg0 += __shfl_xor(vg0, 32);
    vg1 += __shfl_xor(vg1, 16); vg1 += __shfl_xor(vg1, 32);
    if (quad == 0){
      int row0 = m0 + l16, row1 = m0 + 16 + l16;
      if (row0 < M) gate[row0] = vg0;
      if (row1 < M) gate[row1] = vg1;
    }
  }
}

// ---------------- fused edge attention + beta gate (fp8 kv, no-max softmax) ----------------
__global__ __launch_bounds__(256) void k_attn(const _Float16* __restrict__ qh,
                                              const unsigned char* __restrict__ kv8,
                                              const _Float16* __restrict__ rskip,
                                              const float* __restrict__ qwb,
                                              const uint4* __restrict__ edges,
                                              const int* __restrict__ cnt,
                                              const float* __restrict__ We, const float* __restrict__ be,
                                              const float* __restrict__ Wb,
                                              unsigned short* __restrict__ hb,
                                              int loff, int N){
  int tid = threadIdx.x;
  int grp = tid >> 4;
  int n = blockIdx.x*16 + grp;
  bool valid = (n < N);
  int nn = valid ? n : (N-1);
  int w = tid & 15;
  int hh = w & 3, t = w >> 2;
  int cbase = DHEAD*hh + 10*t;
  int slot = hh*4 + t;

  h2 qh2[5];
  {
    const unsigned* qp = (const unsigned*)(qh + (size_t)nn*160 + cbase);
    #pragma unroll
    for (int i = 0; i < 5; ++i) qh2[i] = asH2(qp[i]);
  }
  const float* qwp = qwb + (size_t)nn*20 + hh*5;
  float qw0 = qwp[0], qw1 = qwp[1], qw2 = qwp[2], qw3 = qwp[3], qb = qwp[4];
  h2 qw01 = pk(qw0, qw1), qw23 = pk(qw2, qw3);

  float ssum = 0.f;
  h2 zh = pk(0.f, 0.f);
  h2 acch[5], sah[2];
  #pragma unroll
  for (int i = 0; i < 5; ++i) acch[i] = zh;
  sah[0] = zh; sah[1] = zh;

  int deg = 0;
  if (valid){ deg = cnt[nn]; if (deg > BCAP) deg = BCAP; }
  int st = nn*BCAP;

  uint4 r0 = make_uint4(0,0,0,0), r1 = make_uint4(0,0,0,0);
  uint4 r2 = make_uint4(0,0,0,0), r3 = make_uint4(0,0,0,0);
  i32x4 k0v = {0,0,0,0}, k1v = {0,0,0,0}; int k0e = 0, k1e = 0;
  if (deg > 0) r0 = edges[st];
  if (deg > 1) r1 = edges[st+1];
  if (deg > 2) r2 = edges[st+2];
  if (deg > 3) r3 = edges[st+3];
  if (deg > 0){
    const unsigned char* kp = kv8 + (size_t)r0.x*320 + slot*20;
    k0v = *(const i32x4_a4*)kp; k0e = *(const int*)(kp+16);
  }
  if (deg > 1){
    const unsigned char* kp = kv8 + (size_t)r1.x*320 + slot*20;
    k1v = *(const i32x4_a4*)kp; k1e = *(const int*)(kp+16);
  }

  for (int e = 0; e < deg; e += 2){
    uint4 n0 = make_uint4(0,0,0,0), n1 = make_uint4(0,0,0,0);
    if (e + 4 < deg) n0 = edges[st + e + 4];
    if (e + 5 < deg) n1 = edges[st + e + 5];
    i32x4 k2v = {0,0,0,0}, k3v = {0,0,0,0}; int k2e = 0, k3e = 0;
    if (e + 2 < deg){
      const unsigned char* kp = kv8 + (size_t)r2.x*320 + slot*20;
      k2v = *(const i32x4_a4*)kp; k2e = *(const int*)(kp+16);
    }
    if (e + 3 < deg){
      const unsigned char* kp = kv8 + (size_t)r3.x*320 + slot*20;
      k3v = *(const i32x4_a4*)kp; k3e = *(const int*)(kp+16);
    }
    bool v1 = (e + 1 < deg);
    h2 ea00 = asH2(r0.y), ea01 = asH2(r0.z);
    h2 ea10 = asH2(r1.y), ea11 = asH2(r1.z);
    float p0 = 0.f, p1 = 0.f;
    p0 = fdot2(qh2[0], cvt8(k0v.x), p0);       p1 = fdot2(qh2[0], cvt8(k1v.x), p1);
    p0 = fdot2(qh2[1], cvt8(k0v.x >> 16), p0); p1 = fdot2(qh2[1], cvt8(k1v.x >> 16), p1);
    p0 = fdot2(qh2[2], cvt8(k0v.y), p0);       p1 = fdot2(qh2[2], cvt8(k1v.y), p1);
    p0 = fdot2(qh2[3], cvt8(k0v.y >> 16), p0); p1 = fdot2(qh2[3], cvt8(k1v.y >> 16), p1);
    p0 = fdot2(qh2[4], cvt8(k0v.z), p0);       p1 = fdot2(qh2[4], cvt8(k1v.z), p1);
    p0 += __shfl_xor(p0, 4);                   p1 += __shfl_xor(p1, 4);
    p0 += __shfl_xor(p0, 8);                   p1 += __shfl_xor(p1, 8);
    p0 += qb;                                  p1 += qb;
    p0 = fdot2(ea00, qw01, p0);                p1 = fdot2(ea10, qw01, p1);
    p0 = fdot2(ea01, qw23, p0);                p1 = fdot2(ea11, qw23, p1);

    float ex0 = __expf(p0);
    float ex1 = v1 ? __expf(p1) : 0.f;
    ssum += ex0;
    ssum += ex1;
    h2 eh0 = pk(ex0, ex0), eh1 = pk(ex1, ex1);
    acch[0] += cvt8(k0v.z >> 16)*eh0;  acch[0] += cvt8(k1v.z >> 16)*eh1;
    acch[1] += cvt8(k0v.w)*eh0;        acch[1] += cvt8(k1v.w)*eh1;
    acch[2] += cvt8(k0v.w >> 16)*eh0;  acch[2] += cvt8(k1v.w >> 16)*eh1;
    acch[3] += cvt8(k0e)*eh0;          acch[3] += cvt8(k1e)*eh1;
    acch[4] += cvt8(k0e >> 16)*eh0;    acch[4] += cvt8(k1e >> 16)*eh1;
    sah[0] += ea00*eh0;                sah[0] += ea10*eh1;
    sah[1] += ea01*eh0;                sah[1] += ea11*eh1;

    r0 = r2; r1 = r3; r2 = n0; r3 = n1;
    k0v = k2v; k0e = k2e; k1v = k3v; k1e = k3e;
  }

  {
    float inv = (ssum > 0.f) ? 1.f/ssum : 0.f;
    float sw0 = (float)sah[0].x*inv, sw1 = (float)sah[0].y*inv;
    float sw2 = (float)sah[1].x*inv, sw3 = (float)sah[1].y*inv;
    float bterm = (ssum > 0.f) ? 1.f : 0.f;

    const unsigned* rpu = (const unsigned*)(rskip + (size_t)nn*160 + cbase);
    float o[10];
    float part = 0.f;
    #pragma unroll
    for (int i = 0; i < 5; ++i){
      int c = cbase + 2*i;
      float o0 = (float)acch[i].x*inv + sw0*We[c]   + sw1*We[160+c] + sw2*We[320+c] + sw3*We[480+c] + bterm*be[c];
      float o1 = (float)acch[i].y*inv + sw0*We[c+1] + sw1*We[161+c] + sw2*We[321+c] + sw3*We[481+c] + bterm*be[c+1];
      HU u; u.u = rpu[i];
      float r0f = (float)u.h.x, r1f = (float)u.h.y;
      part += o0*Wb[c]   + r0f*Wb[160+c] + (o0-r0f)*Wb[320+c];
      part += o1*Wb[c+1] + r1f*Wb[161+c] + (o1-r1f)*Wb[321+c];
      o[2*i] = o0; o[2*i+1] = o1;
    }
    part += __shfl_xor(part, 1); part += __shfl_xor(part, 2);
    part += __shfl_xor(part, 4); part += __shfl_xor(part, 8);
    float beta = 1.f/(1.f + __expf(-part));
    if (valid){
      unsigned* hp32 = (unsigned*)(hb + (size_t)nn*JKW + loff);
      #pragma unroll
      for (int i = 0; i < 5; ++i){
        HU u; u.u = rpu[i];
        float r0f = (float)u.h.x, r1f = (float)u.h.y;
        unsigned lo = f2bf(beta*r0f + (1.f-beta)*o[2*i]);
        unsigned hi = f2bf(beta*r1f + (1.f-beta)*o[2*i+1]);
        hp32[cbase/2 + i] = lo | (hi << 16);
      }
    }
  }
}

// ---------------- per-graph gate stats + in-place att normalization ----------------
__global__ __launch_bounds__(256) void k_gatt(float* __restrict__ gate, const int* __restrict__ batch, int N){
  __shared__ float sm[256];
  int g = blockIdx.x, j = threadIdx.x;
  int lo = lbound(batch, N, g), hi = lbound(batch, N, g+1);
  if (hi <= lo) return;
  float m = -INFINITY;
  for (int i = lo + j; i < hi; i += 256) m = fmaxf(m, gate[i]);
  sm[j] = m; __syncthreads();
  #pragma unroll
  for (int off = 128; off; off >>= 1){
    if (j < off) sm[j] = fmaxf(sm[j], sm[j+off]);
    __syncthreads();
  }
  float gm = sm[0]; __syncthreads();
  float s = 0.f;
  for (int i = lo + j; i < hi; i += 256) s += __expf(gate[i] - gm);
  sm[j] = s; __syncthreads();
  #pragma unroll
  for (int off = 128; off; off >>= 1){
    if (j < off) sm[j] += sm[j+off];
    __syncthreads();
  }
  float dg = sm[0];
  float invd = (dg > 0.f) ? 1.f/dg : 0.f;
  for (int i = lo + j; i < hi; i += 256) gate[i] = __expf(gate[i] - gm) * invd;
}

// ---------------- attention pooling: pure weighted accumulation ----------------
__global__ __launch_bounds__(320) void k_pool(const unsigned short* __restrict__ hb, const float* __restrict__ gate,
                                              const int* __restrict__ batch, int N,
                                              float* __restrict__ pooled){
  int g = blockIdx.x, part = blockIdx.y, j = threadIdx.x;
  int lo = lbound(batch, N, g), hi = lbound(batch, N, g+1);
  int len = hi - lo;
  if (len <= 0) return;
  int chunk = (len + (int)gridDim.y - 1) / (int)gridDim.y;
  int a = lo + part*chunk;
  int bnd = a + chunk; if (bnd > hi) bnd = hi;
  if (a >= bnd) return;
  float acc = 0.f;
  #pragma unroll 2
  for (int n = a; n < bnd; ++n){
    acc += gate[n] * bf2f(hb[(size_t)n*JKW + j]);
  }
  atomicAdd(&pooled[g*JKW + j], acc);
}

__global__ __launch_bounds__(320) void k_head(const float* __restrict__ pooled, const float* __restrict__ Wh1,
                                              const float* __restrict__ bh1, const float* __restrict__ Wh2,
                                              const float* __restrict__ bh2, float* __restrict__ out){
  __shared__ float p[320];
  __shared__ float t[320];
  int g = blockIdx.x, tid = threadIdx.x;
  p[tid] = pooled[g*JKW + tid]; __syncthreads();
  float a = bh1[tid];
  for (int i = 0; i < 320; ++i) a += p[i]*Wh1[i*JKW + tid];
  t[tid] = fmaxf(a, 0.f); __syncthreads();
  if (tid < 6){
    float o = bh2[tid];
    for (int j = 0; j < 320; ++j) o += t[j]*Wh2[j*6 + tid];
    out[g*6 + tid] = o;
  }
}

extern "C" void kernel_launch(void* const* d_in, const int* in_sizes, int n_in,
                              void* d_out, int out_size, void* d_ws, size_t ws_size,
                              hipStream_t stream){
  (void)n_in; (void)out_size; (void)ws_size;
  const float* x        = (const float*)d_in[0];
  const int*   eidx     = (const int*)d_in[1];
  const float* edge_attr= (const float*)d_in[2];
  const int*   batch    = (const int*)d_in[3];
  const float* W_in     = (const float*)d_in[4];
  const float* b_in     = (const float*)d_in[5];
  const float* Wq       = (const float*)d_in[6];
  const float* bq       = (const float*)d_in[7];
  const float* Wk       = (const float*)d_in[8];
  const float* bk       = (const float*)d_in[9];
  const float* Wv       = (const float*)d_in[10];
  const float* bv       = (const float*)d_in[11];
  const float* We       = (const float*)d_in[12];
  const float* be       = (const float*)d_in[13];
  const float* Wsk      = (const float*)d_in[14];
  const float* bsk      = (const float*)d_in[15];
  const float* Wb       = (const float*)d_in[16];
  const float* Wg1      = (const float*)d_in[17];
  const float* bg1      = (const float*)d_in[18];
  const float* Wg2      = (const float*)d_in[19];
  const float* Wh1      = (const float*)d_in[21];
  const float* bh1      = (const float*)d_in[22];
  const float* Wh2      = (const float*)d_in[23];
  const float* bh2      = (const float*)d_in[24];

  const int N = in_sizes[0] / 5;
  const int E = in_sizes[1] / 2;
  float* out = (float*)d_out;

  char* w = (char*)d_ws;
  auto alloc = [&](size_t bytes)->char*{ char* p = w; w += (bytes + 255) & ~(size_t)255; return p; };
  unsigned short* hb = (unsigned short*)alloc((size_t)N*JKW*2);
  _Float16* qh  = (_Float16*)alloc((size_t)N*160*2);
  unsigned char* kv8 = (unsigned char*)alloc((size_t)N*320);
  _Float16* rskip = (_Float16*)alloc((size_t)N*160*2);
  float* qwb    = (float*)alloc((size_t)N*20*4);
  unsigned short* Bth  = (unsigned short*)alloc((size_t)2*BCOLS*160*2);
  unsigned short* Btgh = (unsigned short*)alloc((size_t)160*320*2);
  float* bpack  = (float*)alloc((size_t)2*BCOLS*4);
  int*   cnt    = (int*)alloc((size_t)N*4);
  uint4* edges  = (uint4*)alloc((size_t)N*BCAP*16);
  float* gate   = (float*)alloc((size_t)N*4);
  float* pooled = (float*)alloc(NGRAPH*JKW*4);

  const int* srcI = eidx;
  const int* dstI = eidx + E;

  const int NL = (N*20 + 255)/256;
  const int NZ = (N + 255)/256;
  k_pre<<<NL + 1166 + NZ, 256, 0, stream>>>(x, W_in, b_in, hb,
                                            Wq, Wk, Wv, Wsk, bq, bk, bv, bsk, Wg1, We, be,
                                            Bth, bpack, Btgh, cnt, gate, pooled, N);

  const int eb = (E + 255)/256;
  k_fill<<<eb, 256, 0, stream>>>(dstI, srcI, edge_attr, E, cnt, edges);

  const int MB128 = (N + 127)/128;
  for (int l = 0; l < 2; ++l){
    dim3 g1(6, MB128);   // 6 x 128-col panels covering 660 real cols (qkvs + fused qwb)
    k_mgemm<8,1><<<g1, 256, 0, stream>>>(hb, JKW, Bth + (size_t)l*(BCOLS*160), bpack + l*BCOLS,
                                         qh, kv8, rskip, qwb, nullptr, nullptr, N, HIDW);
    k_attn<<<(N + 15)/16, 256, 0, stream>>>(qh, kv8, rskip, qwb, edges, cnt,
                                            We + l*640, be + l*160, Wb + l*480, hb, l*HIDW, N);
  }

  k_mgemm<10,2><<<dim3(1, MB128), 256, 0, stream>>>(hb, JKW, Btgh, bg1, nullptr, nullptr, nullptr, nullptr,
                                                    Wg2, gate, N, JKW);

  k_gatt<<<NGRAPH, 256, 0, stream>>>(gate, batch, N);
  dim3 g3(NGRAPH, 32);
  k_pool<<<g3, 320, 0, stream>>>(hb, gate, batch, N, pooled);
  k_head<<<NGRAPH, 320, 0, stream>>>(pooled, Wh1, bh1, Wh2, bh2, out);
}